// Round 10
// baseline (489.732 us; speedup 1.0000x reference)
//
#include <hip/hip_runtime.h>

#define B_ 16
#define S_ 2048
#define D_ 512
#define MTOT (B_ * S_)

typedef _Float16 half8 __attribute__((ext_vector_type(8)));
typedef _Float16 half4 __attribute__((ext_vector_type(4)));
typedef float floatx4 __attribute__((ext_vector_type(4)));

__device__ __forceinline__ floatx4 mfma16(half8 a, half8 b, floatx4 c) {
    return __builtin_amdgcn_mfma_f32_16x16x32_f16(a, b, c, 0, 0, 0);
}

// async global->LDS, 16B per lane. Per-wave LDS dest must be uniform base + lane*16.
__device__ __forceinline__ void gload16(const void* g, void* l) {
    __builtin_amdgcn_global_load_lds(
        (const __attribute__((address_space(1))) void*)g,
        (__attribute__((address_space(3))) void*)l, 16, 0, 0);
}

// counted-vmcnt + raw barrier + compiler fence (T4 pattern) — proj/scores only
#define WAITB(n) do {                                              \
    asm volatile("s_waitcnt vmcnt(" #n ")" ::: "memory");          \
    __builtin_amdgcn_s_barrier();                                  \
    asm volatile("" ::: "memory");                                 \
} while (0)

// ---------------------------------------------------------------------------
// cvt kernels: fp32 -> fp16, 8 elems/thread.
// ---------------------------------------------------------------------------
__global__ __launch_bounds__(256) void cvt_x_kernel(
    const float* __restrict__ src, _Float16* __restrict__ dst)
{
    const size_t i = ((size_t)blockIdx.x * 256 + threadIdx.x) * 8;
    float4 a = *(const float4*)&src[i];
    float4 b = *(const float4*)&src[i + 4];
    half8 h = { (_Float16)a.x, (_Float16)a.y, (_Float16)a.z, (_Float16)a.w,
                (_Float16)b.x, (_Float16)b.y, (_Float16)b.z, (_Float16)b.w };
    *(half8*)&dst[i] = h;
}

__global__ __launch_bounds__(256) void cvt_w_kernel(
    const float* __restrict__ Wq, const float* __restrict__ Wk,
    const float* __restrict__ Wv, _Float16* __restrict__ dst)
{
    const size_t i = ((size_t)blockIdx.x * 256 + threadIdx.x) * 8;
    const int z = (int)(i >> 18);
    const float* src = (z == 0) ? Wq : ((z == 1) ? Wk : Wv);
    const size_t off = i & 262143;
    float4 a = *(const float4*)&src[off];
    float4 b = *(const float4*)&src[off + 4];
    half8 h = { (_Float16)a.x, (_Float16)a.y, (_Float16)a.z, (_Float16)a.w,
                (_Float16)b.x, (_Float16)b.y, (_Float16)b.z, (_Float16)b.w };
    *(half8*)&dst[i] = h;
}

// ---------------------------------------------------------------------------
// Kernel 1: projection GEMMs, 3-buffer counted-vmcnt pipeline.
// z==0 -> Qh[m][e]; z==1 -> Kh[m][e] (pre-scaled 1/sqrt(D)); z==2 -> Vt[b][e][s]
// ---------------------------------------------------------------------------
__global__ __launch_bounds__(256) void proj2_kernel(
    const _Float16* __restrict__ xh, const _Float16* __restrict__ wh3,
    const float* __restrict__ bq, const float* __restrict__ bk,
    const float* __restrict__ bv,
    _Float16* __restrict__ Qh, _Float16* __restrict__ Kh,
    _Float16* __restrict__ Vt)
{
    const int z = blockIdx.z;
    const float* bias = (z == 0) ? bq : ((z == 1) ? bk : bv);
    _Float16* out = (z == 0) ? Qh : ((z == 1) ? Kh : Vt);
    const _Float16* Wz = wh3 + (size_t)z * D_ * D_;

    __shared__ _Float16 Ah[3][128 * 32];
    __shared__ _Float16 Bh[3][128 * 32];
    const int t = threadIdx.x;
    const int l = t & 63;
    const int wv = t >> 6;
    const int wrO = (wv >> 1) * 64;
    const int wcO = (wv & 1) * 64;
    const int fr = l & 15;
    const int fk = (l >> 4) * 8;
    const int mBase = blockIdx.y * 128;
    const int eBase = blockIdx.x * 128;

    const int f0 = t, f1 = t + 256;
    const int r0 = f0 >> 2, c0 = (f0 & 3) ^ ((r0 >> 1) & 3);
    const int r1 = f1 >> 2, c1 = (f1 & 3) ^ ((r1 >> 1) & 3);

#define STAGE_PROJ(buf, kk) do {                                               \
    gload16(&xh[(size_t)(mBase + r0) * D_ + (kk) + c0 * 8], (char*)Ah[buf] + f0 * 16); \
    gload16(&xh[(size_t)(mBase + r1) * D_ + (kk) + c1 * 8], (char*)Ah[buf] + f1 * 16); \
    gload16(&Wz[(size_t)(eBase + r0) * D_ + (kk) + c0 * 8], (char*)Bh[buf] + f0 * 16); \
    gload16(&Wz[(size_t)(eBase + r1) * D_ + (kk) + c1 * 8], (char*)Bh[buf] + f1 * 16); \
} while (0)

    floatx4 acc[4][4] = {};

    STAGE_PROJ(0, 0);
    STAGE_PROJ(1, 32);
    for (int step = 0; step < 16; ++step) {
        if (step < 15) WAITB(4); else WAITB(0);
        if (step < 14) STAGE_PROJ((step + 2) % 3, (step + 2) * 32);
        const int cur = step % 3;
        half8 af[4], bf[4];
        #pragma unroll
        for (int mi = 0; mi < 4; ++mi) {
            int row = wrO + mi * 16 + fr;
            int c = (fk >> 3) ^ ((row >> 1) & 3);
            af[mi] = *(half8*)&Ah[cur][row * 32 + c * 8];
        }
        #pragma unroll
        for (int ni = 0; ni < 4; ++ni) {
            int row = wcO + ni * 16 + fr;
            int c = (fk >> 3) ^ ((row >> 1) & 3);
            bf[ni] = *(half8*)&Bh[cur][row * 32 + c * 8];
        }
        __builtin_amdgcn_s_setprio(1);
        #pragma unroll
        for (int mi = 0; mi < 4; ++mi)
            #pragma unroll
            for (int ni = 0; ni < 4; ++ni)
                acc[mi][ni] = mfma16(af[mi], bf[ni], acc[mi][ni]);
        __builtin_amdgcn_s_setprio(0);
    }
#undef STAGE_PROJ

    const float kscale = (z == 1) ? 0.044194173824159216f : 1.0f;  // 1/sqrt(512)
    #pragma unroll
    for (int mi = 0; mi < 4; ++mi) {
        #pragma unroll
        for (int ni = 0; ni < 4; ++ni) {
            const int col  = eBase + wcO + ni * 16 + fr;
            const int row0 = mBase + wrO + mi * 16 + (l >> 4) * 4;
            const float bv_ = bias[col];
            if (z != 2) {
                #pragma unroll
                for (int j = 0; j < 4; ++j)
                    out[(size_t)(row0 + j) * D_ + col] =
                        (_Float16)((acc[mi][ni][j] + bv_) * kscale);
            } else {
                const int b = row0 >> 11;
                const int s = row0 & (S_ - 1);
                half4 h;
                #pragma unroll
                for (int j = 0; j < 4; ++j) h[j] = (_Float16)(acc[mi][ni][j] + bv_);
                *(half4*)&out[((size_t)b * D_ + col) * S_ + s] = h;
            }
        }
    }
}

// ---------------------------------------------------------------------------
// Kernel 2: scores + per-block softmax partials.  3-buffer counted-vmcnt
// pipeline + bijective XCD swizzle.  1D grid 4096 = 16 qx * 16 kblk * 16 b.
// ---------------------------------------------------------------------------
__global__ __launch_bounds__(256) void scores_kernel(
    const _Float16* __restrict__ Qh, const _Float16* __restrict__ Kh,
    float* __restrict__ Wout, float2* __restrict__ stats)
{
    __shared__ _Float16 Ah[3][128 * 32];  // K tile
    __shared__ _Float16 Bh[3][128 * 32];  // Q tile
    __shared__ float smR[4][64];
    const int t = threadIdx.x;
    const int l = t & 63;
    const int wv = t >> 6;
    const int wrO = (wv >> 1) * 64;
    const int wcO = (wv & 1) * 64;
    const int fr = l & 15;
    const int fk = (l >> 4) * 8;

    const int orig = blockIdx.x;
    const int wg = (orig & 7) * 512 + (orig >> 3);
    const int qx = wg & 15;
    const int kblk = (wg >> 4) & 15;
    const int b = wg >> 8;
    const int kBase = kblk * 128;
    const int qBase = qx * 128;
    const _Float16* Kb = Kh + (size_t)b * S_ * D_;
    const _Float16* Qb = Qh + (size_t)b * S_ * D_;

    const int f0 = t, f1 = t + 256;
    const int r0 = f0 >> 2, c0 = (f0 & 3) ^ ((r0 >> 1) & 3);
    const int r1 = f1 >> 2, c1 = (f1 & 3) ^ ((r1 >> 1) & 3);

#define STAGE_SC(buf, kk) do {                                                 \
    gload16(&Kb[(size_t)(kBase + r0) * D_ + (kk) + c0 * 8], (char*)Ah[buf] + f0 * 16); \
    gload16(&Kb[(size_t)(kBase + r1) * D_ + (kk) + c1 * 8], (char*)Ah[buf] + f1 * 16); \
    gload16(&Qb[(size_t)(qBase + r0) * D_ + (kk) + c0 * 8], (char*)Bh[buf] + f0 * 16); \
    gload16(&Qb[(size_t)(qBase + r1) * D_ + (kk) + c1 * 8], (char*)Bh[buf] + f1 * 16); \
} while (0)

    floatx4 acc[4][4] = {};

    STAGE_SC(0, 0);
    STAGE_SC(1, 32);
    for (int step = 0; step < 16; ++step) {
        if (step < 15) WAITB(4); else WAITB(0);
        if (step < 14) STAGE_SC((step + 2) % 3, (step + 2) * 32);
        const int cur = step % 3;
        half8 af[4], bf[4];
        #pragma unroll
        for (int mi = 0; mi < 4; ++mi) {
            int row = wrO + mi * 16 + fr;
            int c = (fk >> 3) ^ ((row >> 1) & 3);
            af[mi] = *(half8*)&Ah[cur][row * 32 + c * 8];
        }
        #pragma unroll
        for (int ni = 0; ni < 4; ++ni) {
            int row = wcO + ni * 16 + fr;
            int c = (fk >> 3) ^ ((row >> 1) & 3);
            bf[ni] = *(half8*)&Bh[cur][row * 32 + c * 8];
        }
        __builtin_amdgcn_s_setprio(1);
        #pragma unroll
        for (int mi = 0; mi < 4; ++mi)
            #pragma unroll
            for (int ni = 0; ni < 4; ++ni)
                acc[mi][ni] = mfma16(af[mi], bf[ni], acc[mi][ni]);
        __builtin_amdgcn_s_setprio(0);
    }
#undef STAGE_SC

    // ---- epilogue: per-q block max over k, e = exp, block sum, stats.
    float pm[4];
    #pragma unroll
    for (int ni = 0; ni < 4; ++ni) {
        float m = -1e30f;
        #pragma unroll
        for (int mi = 0; mi < 4; ++mi)
            #pragma unroll
            for (int j = 0; j < 4; ++j) m = fmaxf(m, acc[mi][ni][j]);
        pm[ni] = m;
    }
    #pragma unroll
    for (int ni = 0; ni < 4; ++ni) {
        pm[ni] = fmaxf(pm[ni], __shfl_xor(pm[ni], 16));
        pm[ni] = fmaxf(pm[ni], __shfl_xor(pm[ni], 32));
    }
    if (l < 16) {
        #pragma unroll
        for (int ni = 0; ni < 4; ++ni) smR[wv][ni * 16 + l] = pm[ni];
    }
    __syncthreads();
    float mb[4], ps[4];
    #pragma unroll
    for (int ni = 0; ni < 4; ++ni)
        mb[ni] = fmaxf(smR[wv & 1][ni * 16 + fr], smR[(wv & 1) + 2][ni * 16 + fr]);
    #pragma unroll
    for (int ni = 0; ni < 4; ++ni) {
        float s = 0.f;
        #pragma unroll
        for (int mi = 0; mi < 4; ++mi)
            #pragma unroll
            for (int j = 0; j < 4; ++j) {
                float e = __expf(acc[mi][ni][j] - mb[ni]);
                acc[mi][ni][j] = e;
                s += e;
            }
        ps[ni] = s;
    }
    #pragma unroll
    for (int ni = 0; ni < 4; ++ni) {
        ps[ni] += __shfl_xor(ps[ni], 16);
        ps[ni] += __shfl_xor(ps[ni], 32);
    }
    __syncthreads();
    if (l < 16) {
        #pragma unroll
        for (int ni = 0; ni < 4; ++ni) smR[wv][ni * 16 + l] = ps[ni];
    }
    __syncthreads();
    if (wv < 2 && l < 16) {
        #pragma unroll
        for (int ni = 0; ni < 4; ++ni) {
            const int ql = wv * 64 + ni * 16 + l;
            float sb = smR[wv][ni * 16 + l] + smR[wv + 2][ni * 16 + l];
            float2 st; st.x = mb[ni]; st.y = sb;
            stats[(size_t)(b * 16 + kblk) * S_ + qBase + ql] = st;
        }
    }

    #pragma unroll
    for (int mi = 0; mi < 4; ++mi) {
        #pragma unroll
        for (int ni = 0; ni < 4; ++ni) {
            const int krow0 = kBase + wrO + mi * 16 + (l >> 4) * 4;
            const int qcol  = qBase + wcO + ni * 16 + fr;
            half4 h = { (_Float16)acc[mi][ni][0], (_Float16)acc[mi][ni][1],
                        (_Float16)acc[mi][ni][2], (_Float16)acc[mi][ni][3] };
            char* p = (char*)Wout + ((size_t)b * S_ + qcol) * (S_ * 4) + 4096 + 2 * krow0;
            *(half4*)p = h;
        }
    }
}

// ---------------------------------------------------------------------------
// Kernel 3: PV only, register-lean.  Grid 1024 = 2 dg x 32 qx x 16 b.
// Wave owns 32 d-rows (acc[2][4] = 32 AGPR).  V loaded DIRECT global->VGPR
// (L2-hot, per-lane A-frag addressing).  Only the 4KB e-tile goes through
// LDS (dbuf + __syncthreads).  No global stores in the loop (wfin does w).
// ---------------------------------------------------------------------------
__global__ __launch_bounds__(512) void pv7(
    const float* __restrict__ Wt, const _Float16* __restrict__ Vt,
    const float2* __restrict__ stats, float* __restrict__ Out)
{
    __shared__ _Float16 Wh[2][64 * 32];    // 8KB
    __shared__ float smScale[16][64];      // 4KB

    const int t = threadIdx.x;
    const int l = t & 63;
    const int wv = t >> 6;
    // XCD swizzle: nwg=1024 -> 128 blocks/XCD chunk (bijective)
    const int orig = blockIdx.x;
    const int wg = (orig & 7) * 128 + (orig >> 3);
    const int dg = wg & 1;
    const int qx = (wg >> 1) & 31;
    const int b = wg >> 6;
    const int qBase = qx * 64;
    const char* WbB = (const char*)Wt + ((size_t)b * S_ + qBase) * (S_ * 4);
    const _Float16* Vb = Vt + (size_t)b * D_ * S_;

    const int fr = l & 15;
    const int fk4 = l >> 4;
    const bool doE = (wv < 4);
    const int ge = (wv & 3) * 64 + l;
    const int er = ge >> 2;
    const int es = (ge & 3) ^ ((er >> 1) & 3);

    // ---- Phase A: per-q softmax stats combine
    if (t < 64) {
        float mkb[16], skb[16];
        float m = -1e30f;
        #pragma unroll
        for (int kb = 0; kb < 16; ++kb) {
            float2 st = stats[(size_t)(b * 16 + kb) * S_ + qBase + t];
            mkb[kb] = st.x; skb[kb] = st.y;
            m = fmaxf(m, st.x);
        }
        float s = 0.f;
        #pragma unroll
        for (int kb = 0; kb < 16; ++kb) {
            mkb[kb] = __expf(mkb[kb] - m);
            s += skb[kb] * mkb[kb];
        }
        const float inv = 1.0f / s;
        #pragma unroll
        for (int kb = 0; kb < 16; ++kb) smScale[kb][t] = mkb[kb] * inv;
    }

    // V row pointers for this wave's 2 A-frags (rows dg*256 + wv*32 + mi*16 + fr)
    const _Float16* vp0 = Vb + (size_t)(dg * 256 + wv * 32 + fr) * S_ + fk4 * 8;
    const _Float16* vp1 = vp0 + (size_t)16 * S_;

    floatx4 acc[2][4] = {};

    if (doE)
        gload16(WbB + (size_t)er * 8192 + 4096 + es * 16, (char*)Wh[0] + ge * 16);
    __syncthreads();   // publishes smScale + Wh[0]

    for (int step = 0; step < 64; ++step) {
        const int cur = step & 1;
        const int kk = step * 32;
        const int kblk = kk >> 7;
        if (step < 63 && doE)
            gload16(WbB + (size_t)er * 8192 + 4096 + 2 * (kk + 32) + es * 16,
                    (char*)Wh[cur ^ 1] + ge * 16);
        half8 af0 = *(const half8*)(vp0 + kk);
        half8 af1 = *(const half8*)(vp1 + kk);
        half8 bf[4];
        #pragma unroll
        for (int ni = 0; ni < 4; ++ni) {
            int row = ni * 16 + fr;
            int c = fk4 ^ ((row >> 1) & 3);
            bf[ni] = *(half8*)&Wh[cur][row * 32 + c * 8];
            const _Float16 sch = (_Float16)smScale[kblk][row];
            #pragma unroll
            for (int j = 0; j < 8; ++j) bf[ni][j] *= sch;
        }
        #pragma unroll
        for (int ni = 0; ni < 4; ++ni) {
            acc[0][ni] = mfma16(af0, bf[ni], acc[0][ni]);
            acc[1][ni] = mfma16(af1, bf[ni], acc[1][ni]);
        }
        __syncthreads();
    }

    #pragma unroll
    for (int mi = 0; mi < 2; ++mi) {
        #pragma unroll
        for (int ni = 0; ni < 4; ++ni) {
            const int d0 = dg * 256 + wv * 32 + mi * 16 + (l >> 4) * 4;
            const int q  = qBase + ni * 16 + fr;
            float4 v;
            v.x = acc[mi][ni][0];
            v.y = acc[mi][ni][1];
            v.z = acc[mi][ni][2];
            v.w = acc[mi][ni][3];
            *(float4*)&Out[((size_t)b * S_ + q) * D_ + d0] = v;
        }
    }
}

// ---------------------------------------------------------------------------
// Kernel 4: weights finalize (pure streaming).  wave owns whole q-rows:
// read e fp16 (upper half of row), scale, write full fp32 row in place.
// ---------------------------------------------------------------------------
__global__ __launch_bounds__(256) void wfin(
    float* __restrict__ Wt, const float2* __restrict__ stats)
{
    const int t = threadIdx.x;
    const int l = t & 63;
    const int wv = t >> 6;
    const int wid = blockIdx.x * 4 + wv;          // 0..8191

    for (int rr = 0; rr < 4; ++rr) {
        const int row = wid + rr * 8192;          // 0..32767
        const int b = row >> 11, q = row & (S_ - 1);

        float mkb[16], skb[16];
        float m = -1e30f;
        #pragma unroll
        for (int kb = 0; kb < 16; ++kb) {
            float2 st = stats[(size_t)(b * 16 + kb) * S_ + q];
            mkb[kb] = st.x; skb[kb] = st.y;
            m = fmaxf(m, st.x);
        }
        float s = 0.f;
        #pragma unroll
        for (int kb = 0; kb < 16; ++kb) {
            mkb[kb] = __expf(mkb[kb] - m);
            s += skb[kb] * mkb[kb];
        }
        const float inv = 1.0f / s;

        char* rowp = (char*)Wt + (size_t)row * (S_ * 4);
        half4 eh[8];
        #pragma unroll
        for (int j = 0; j < 8; ++j)
            eh[j] = *(const half4*)(rowp + 4096 + j * 512 + 8 * l);
        float4 w[8];
        #pragma unroll
        for (int j = 0; j < 8; ++j) {
            const float sc = mkb[2 * j + (l >> 5)] * inv;
            w[j].x = (float)eh[j][0] * sc;
            w[j].y = (float)eh[j][1] * sc;
            w[j].z = (float)eh[j][2] * sc;
            w[j].w = (float)eh[j][3] * sc;
        }
        // all e loads must complete before any in-place overwrite
        asm volatile("s_waitcnt vmcnt(0)" ::: "memory");
        #pragma unroll
        for (int j = 0; j < 8; ++j)
            *(float4*)(rowp + j * 1024 + 16 * l) = w[j];
    }
}

// ---------------------------------------------------------------------------
extern "C" void kernel_launch(void* const* d_in, const int* in_sizes, int n_in,
                              void* d_out, int out_size, void* d_ws, size_t ws_size,
                              hipStream_t stream)
{
    const float* x  = (const float*)d_in[0];
    const float* Wq = (const float*)d_in[1];
    const float* bq = (const float*)d_in[2];
    const float* Wk = (const float*)d_in[3];
    const float* bk = (const float*)d_in[4];
    const float* Wv = (const float*)d_in[5];
    const float* bv = (const float*)d_in[6];

    float* out = (float*)d_out;                       // [16,2048,512]
    float* wts = out + (size_t)B_ * S_ * D_;          // [16,2048,2048]

    _Float16* Qh = (_Float16*)d_ws;                   // 32 MB
    _Float16* Kh = Qh + (size_t)MTOT * D_;            // 32 MB
    _Float16* Vt = Kh + (size_t)MTOT * D_;            // 32 MB
    float2* stats = (float2*)(Vt + (size_t)MTOT * D_); // 4 MB

    // fp16 scratch inside the weights output region (dead until scores runs)
    _Float16* xh  = (_Float16*)wts;                   // 33.5 MB
    _Float16* wh3 = xh + (size_t)MTOT * D_;           // 1.5 MB

    cvt_x_kernel<<<MTOT * D_ / (256 * 8), 256, 0, stream>>>(x, xh);
    cvt_w_kernel<<<3 * D_ * D_ / (256 * 8), 256, 0, stream>>>(Wq, Wk, Wv, wh3);
    proj2_kernel<<<dim3(D_ / 128, MTOT / 128, 3), 256, 0, stream>>>(
        xh, wh3, bq, bk, bv, Qh, Kh, Vt);
    scores_kernel<<<4096, 256, 0, stream>>>(Qh, Kh, wts, stats);
    pv7<<<1024, 512, 0, stream>>>(wts, Vt, stats, out);
    wfin<<<2048, 256, 0, stream>>>(wts, stats);
}

// Round 11
// 473.359 us; speedup vs baseline: 1.0346x; 1.0346x over previous
//
#include <hip/hip_runtime.h>

#define B_ 16
#define S_ 2048
#define D_ 512
#define MTOT (B_ * S_)

typedef _Float16 half8 __attribute__((ext_vector_type(8)));
typedef _Float16 half4 __attribute__((ext_vector_type(4)));
typedef float floatx4 __attribute__((ext_vector_type(4)));

__device__ __forceinline__ floatx4 mfma16(half8 a, half8 b, floatx4 c) {
    return __builtin_amdgcn_mfma_f32_16x16x32_f16(a, b, c, 0, 0, 0);
}

// async global->LDS, 16B per lane. Per-wave LDS dest must be uniform base + lane*16.
__device__ __forceinline__ void gload16(const void* g, void* l) {
    __builtin_amdgcn_global_load_lds(
        (const __attribute__((address_space(1))) void*)g,
        (__attribute__((address_space(3))) void*)l, 16, 0, 0);
}

// counted-vmcnt + raw barrier + compiler fence (T4 pattern)
#define WAITB(n) do {                                              \
    asm volatile("s_waitcnt vmcnt(" #n ")" ::: "memory");          \
    __builtin_amdgcn_s_barrier();                                  \
    asm volatile("" ::: "memory");                                 \
} while (0)

// ---------------------------------------------------------------------------
// cvt kernels: fp32 -> fp16, 8 elems/thread.
// ---------------------------------------------------------------------------
__global__ __launch_bounds__(256) void cvt_x_kernel(
    const float* __restrict__ src, _Float16* __restrict__ dst)
{
    const size_t i = ((size_t)blockIdx.x * 256 + threadIdx.x) * 8;
    float4 a = *(const float4*)&src[i];
    float4 b = *(const float4*)&src[i + 4];
    half8 h = { (_Float16)a.x, (_Float16)a.y, (_Float16)a.z, (_Float16)a.w,
                (_Float16)b.x, (_Float16)b.y, (_Float16)b.z, (_Float16)b.w };
    *(half8*)&dst[i] = h;
}

__global__ __launch_bounds__(256) void cvt_w_kernel(
    const float* __restrict__ Wq, const float* __restrict__ Wk,
    const float* __restrict__ Wv, _Float16* __restrict__ dst)
{
    const size_t i = ((size_t)blockIdx.x * 256 + threadIdx.x) * 8;
    const int z = (int)(i >> 18);
    const float* src = (z == 0) ? Wq : ((z == 1) ? Wk : Wv);
    const size_t off = i & 262143;
    float4 a = *(const float4*)&src[off];
    float4 b = *(const float4*)&src[off + 4];
    half8 h = { (_Float16)a.x, (_Float16)a.y, (_Float16)a.z, (_Float16)a.w,
                (_Float16)b.x, (_Float16)b.y, (_Float16)b.z, (_Float16)b.w };
    *(half8*)&dst[i] = h;
}

// ---------------------------------------------------------------------------
// Kernel 1: projection GEMMs, 3-buffer counted-vmcnt pipeline.
// z==0 -> Qh[m][e]; z==1 -> Kh[m][e] (pre-scaled 1/sqrt(D)); z==2 -> Vt[b][e][s]
// ---------------------------------------------------------------------------
__global__ __launch_bounds__(256) void proj2_kernel(
    const _Float16* __restrict__ xh, const _Float16* __restrict__ wh3,
    const float* __restrict__ bq, const float* __restrict__ bk,
    const float* __restrict__ bv,
    _Float16* __restrict__ Qh, _Float16* __restrict__ Kh,
    _Float16* __restrict__ Vt)
{
    const int z = blockIdx.z;
    const float* bias = (z == 0) ? bq : ((z == 1) ? bk : bv);
    _Float16* out = (z == 0) ? Qh : ((z == 1) ? Kh : Vt);
    const _Float16* Wz = wh3 + (size_t)z * D_ * D_;

    __shared__ _Float16 Ah[3][128 * 32];
    __shared__ _Float16 Bh[3][128 * 32];
    const int t = threadIdx.x;
    const int l = t & 63;
    const int wv = t >> 6;
    const int wrO = (wv >> 1) * 64;
    const int wcO = (wv & 1) * 64;
    const int fr = l & 15;
    const int fk = (l >> 4) * 8;
    const int mBase = blockIdx.y * 128;
    const int eBase = blockIdx.x * 128;

    const int f0 = t, f1 = t + 256;
    const int r0 = f0 >> 2, c0 = (f0 & 3) ^ ((r0 >> 1) & 3);
    const int r1 = f1 >> 2, c1 = (f1 & 3) ^ ((r1 >> 1) & 3);

#define STAGE_PROJ(buf, kk) do {                                               \
    gload16(&xh[(size_t)(mBase + r0) * D_ + (kk) + c0 * 8], (char*)Ah[buf] + f0 * 16); \
    gload16(&xh[(size_t)(mBase + r1) * D_ + (kk) + c1 * 8], (char*)Ah[buf] + f1 * 16); \
    gload16(&Wz[(size_t)(eBase + r0) * D_ + (kk) + c0 * 8], (char*)Bh[buf] + f0 * 16); \
    gload16(&Wz[(size_t)(eBase + r1) * D_ + (kk) + c1 * 8], (char*)Bh[buf] + f1 * 16); \
} while (0)

    floatx4 acc[4][4] = {};

    STAGE_PROJ(0, 0);
    STAGE_PROJ(1, 32);
    for (int step = 0; step < 16; ++step) {
        if (step < 15) WAITB(4); else WAITB(0);
        if (step < 14) STAGE_PROJ((step + 2) % 3, (step + 2) * 32);
        const int cur = step % 3;
        half8 af[4], bf[4];
        #pragma unroll
        for (int mi = 0; mi < 4; ++mi) {
            int row = wrO + mi * 16 + fr;
            int c = (fk >> 3) ^ ((row >> 1) & 3);
            af[mi] = *(half8*)&Ah[cur][row * 32 + c * 8];
        }
        #pragma unroll
        for (int ni = 0; ni < 4; ++ni) {
            int row = wcO + ni * 16 + fr;
            int c = (fk >> 3) ^ ((row >> 1) & 3);
            bf[ni] = *(half8*)&Bh[cur][row * 32 + c * 8];
        }
        __builtin_amdgcn_s_setprio(1);
        #pragma unroll
        for (int mi = 0; mi < 4; ++mi)
            #pragma unroll
            for (int ni = 0; ni < 4; ++ni)
                acc[mi][ni] = mfma16(af[mi], bf[ni], acc[mi][ni]);
        __builtin_amdgcn_s_setprio(0);
    }
#undef STAGE_PROJ

    const float kscale = (z == 1) ? 0.044194173824159216f : 1.0f;  // 1/sqrt(512)
    #pragma unroll
    for (int mi = 0; mi < 4; ++mi) {
        #pragma unroll
        for (int ni = 0; ni < 4; ++ni) {
            const int col  = eBase + wcO + ni * 16 + fr;
            const int row0 = mBase + wrO + mi * 16 + (l >> 4) * 4;
            const float bv_ = bias[col];
            if (z != 2) {
                #pragma unroll
                for (int j = 0; j < 4; ++j)
                    out[(size_t)(row0 + j) * D_ + col] =
                        (_Float16)((acc[mi][ni][j] + bv_) * kscale);
            } else {
                const int b = row0 >> 11;
                const int s = row0 & (S_ - 1);
                half4 h;
                #pragma unroll
                for (int j = 0; j < 4; ++j) h[j] = (_Float16)(acc[mi][ni][j] + bv_);
                *(half4*)&out[((size_t)b * D_ + col) * S_ + s] = h;
            }
        }
    }
}

// ---------------------------------------------------------------------------
// Kernel 2: scores + per-block softmax partials.  3-buffer counted-vmcnt
// pipeline + bijective XCD swizzle.  1D grid 4096 = 16 qx * 16 kblk * 16 b.
// ---------------------------------------------------------------------------
__global__ __launch_bounds__(256) void scores_kernel(
    const _Float16* __restrict__ Qh, const _Float16* __restrict__ Kh,
    float* __restrict__ Wout, float2* __restrict__ stats)
{
    __shared__ _Float16 Ah[3][128 * 32];  // K tile
    __shared__ _Float16 Bh[3][128 * 32];  // Q tile
    __shared__ float smR[4][64];
    const int t = threadIdx.x;
    const int l = t & 63;
    const int wv = t >> 6;
    const int wrO = (wv >> 1) * 64;
    const int wcO = (wv & 1) * 64;
    const int fr = l & 15;
    const int fk = (l >> 4) * 8;

    const int orig = blockIdx.x;
    const int wg = (orig & 7) * 512 + (orig >> 3);
    const int qx = wg & 15;
    const int kblk = (wg >> 4) & 15;
    const int b = wg >> 8;
    const int kBase = kblk * 128;
    const int qBase = qx * 128;
    const _Float16* Kb = Kh + (size_t)b * S_ * D_;
    const _Float16* Qb = Qh + (size_t)b * S_ * D_;

    const int f0 = t, f1 = t + 256;
    const int r0 = f0 >> 2, c0 = (f0 & 3) ^ ((r0 >> 1) & 3);
    const int r1 = f1 >> 2, c1 = (f1 & 3) ^ ((r1 >> 1) & 3);

#define STAGE_SC(buf, kk) do {                                                 \
    gload16(&Kb[(size_t)(kBase + r0) * D_ + (kk) + c0 * 8], (char*)Ah[buf] + f0 * 16); \
    gload16(&Kb[(size_t)(kBase + r1) * D_ + (kk) + c1 * 8], (char*)Ah[buf] + f1 * 16); \
    gload16(&Qb[(size_t)(qBase + r0) * D_ + (kk) + c0 * 8], (char*)Bh[buf] + f0 * 16); \
    gload16(&Qb[(size_t)(qBase + r1) * D_ + (kk) + c1 * 8], (char*)Bh[buf] + f1 * 16); \
} while (0)

    floatx4 acc[4][4] = {};

    STAGE_SC(0, 0);
    STAGE_SC(1, 32);
    for (int step = 0; step < 16; ++step) {
        if (step < 15) WAITB(4); else WAITB(0);
        if (step < 14) STAGE_SC((step + 2) % 3, (step + 2) * 32);
        const int cur = step % 3;
        half8 af[4], bf[4];
        #pragma unroll
        for (int mi = 0; mi < 4; ++mi) {
            int row = wrO + mi * 16 + fr;
            int c = (fk >> 3) ^ ((row >> 1) & 3);
            af[mi] = *(half8*)&Ah[cur][row * 32 + c * 8];
        }
        #pragma unroll
        for (int ni = 0; ni < 4; ++ni) {
            int row = wcO + ni * 16 + fr;
            int c = (fk >> 3) ^ ((row >> 1) & 3);
            bf[ni] = *(half8*)&Bh[cur][row * 32 + c * 8];
        }
        __builtin_amdgcn_s_setprio(1);
        #pragma unroll
        for (int mi = 0; mi < 4; ++mi)
            #pragma unroll
            for (int ni = 0; ni < 4; ++ni)
                acc[mi][ni] = mfma16(af[mi], bf[ni], acc[mi][ni]);
        __builtin_amdgcn_s_setprio(0);
    }
#undef STAGE_SC

    // ---- epilogue: per-q block max over k, e = exp, block sum, stats.
    float pm[4];
    #pragma unroll
    for (int ni = 0; ni < 4; ++ni) {
        float m = -1e30f;
        #pragma unroll
        for (int mi = 0; mi < 4; ++mi)
            #pragma unroll
            for (int j = 0; j < 4; ++j) m = fmaxf(m, acc[mi][ni][j]);
        pm[ni] = m;
    }
    #pragma unroll
    for (int ni = 0; ni < 4; ++ni) {
        pm[ni] = fmaxf(pm[ni], __shfl_xor(pm[ni], 16));
        pm[ni] = fmaxf(pm[ni], __shfl_xor(pm[ni], 32));
    }
    if (l < 16) {
        #pragma unroll
        for (int ni = 0; ni < 4; ++ni) smR[wv][ni * 16 + l] = pm[ni];
    }
    __syncthreads();
    float mb[4], ps[4];
    #pragma unroll
    for (int ni = 0; ni < 4; ++ni)
        mb[ni] = fmaxf(smR[wv & 1][ni * 16 + fr], smR[(wv & 1) + 2][ni * 16 + fr]);
    #pragma unroll
    for (int ni = 0; ni < 4; ++ni) {
        float s = 0.f;
        #pragma unroll
        for (int mi = 0; mi < 4; ++mi)
            #pragma unroll
            for (int j = 0; j < 4; ++j) {
                float e = __expf(acc[mi][ni][j] - mb[ni]);
                acc[mi][ni][j] = e;
                s += e;
            }
        ps[ni] = s;
    }
    #pragma unroll
    for (int ni = 0; ni < 4; ++ni) {
        ps[ni] += __shfl_xor(ps[ni], 16);
        ps[ni] += __shfl_xor(ps[ni], 32);
    }
    __syncthreads();
    if (l < 16) {
        #pragma unroll
        for (int ni = 0; ni < 4; ++ni) smR[wv][ni * 16 + l] = ps[ni];
    }
    __syncthreads();
    if (wv < 2 && l < 16) {
        #pragma unroll
        for (int ni = 0; ni < 4; ++ni) {
            const int ql = wv * 64 + ni * 16 + l;
            float sb = smR[wv][ni * 16 + l] + smR[wv + 2][ni * 16 + l];
            float2 st; st.x = mb[ni]; st.y = sb;
            stats[(size_t)(b * 16 + kblk) * S_ + qBase + ql] = st;
        }
    }

    #pragma unroll
    for (int mi = 0; mi < 4; ++mi) {
        #pragma unroll
        for (int ni = 0; ni < 4; ++ni) {
            const int krow0 = kBase + wrO + mi * 16 + (l >> 4) * 4;
            const int qcol  = qBase + wcO + ni * 16 + fr;
            half4 h = { (_Float16)acc[mi][ni][0], (_Float16)acc[mi][ni][1],
                        (_Float16)acc[mi][ni][2], (_Float16)acc[mi][ni][3] };
            char* p = (char*)Wout + ((size_t)b * S_ + qcol) * (S_ * 4) + 4096 + 2 * krow0;
            *(half4*)p = h;
        }
    }
}

// ---------------------------------------------------------------------------
// Kernel 3: PV + fused fp32 weights write (pv4 geometry), with the w-store
// exempted from the barrier drain: per step
//   {STAGE(s+1) [5 vmem] -> w-store(s) [newest vmem] -> MFMA -> vmcnt(1) -> bar}
// vmcnt(1) drains all stage ops (required for LDS publish) but leaves the
// w-store in flight, so the 268MB store stream never blocks the loop.
// 76KB LDS + 124 arch-regs -> 2 blocks/CU.  Grid 512, XCD-swizzled.
// ---------------------------------------------------------------------------
__global__ __launch_bounds__(512) void pv8(
    float* __restrict__ Wt, const _Float16* __restrict__ Vt,
    const float2* __restrict__ stats, float* __restrict__ Out)
{
    __shared__ _Float16 Vh[2][512 * 32];   // 64KB
    __shared__ _Float16 Wh[2][64 * 32];    // 8KB
    __shared__ float smScale[16][64];      // 4KB

    const int t = threadIdx.x;
    const int l = t & 63;
    const int wv = t >> 6;
    // XCD swizzle: nwg=512 -> 64 blocks/XCD chunk
    const int orig = blockIdx.x;
    const int wg = (orig & 7) * 64 + (orig >> 3);
    const int qx = wg & 31;
    const int b = wg >> 5;
    const int qBase = qx * 64;
    char* WbB = (char*)Wt + ((size_t)b * S_ + qBase) * (S_ * 4);  // row stride 8192B
    const _Float16* Vb = Vt + (size_t)b * D_ * S_;

    const int fr = l & 15;
    const int fk4 = l >> 4;
    const bool doE = (wv < 4);
    const int ge = (wv & 3) * 64 + l;
    const int er = ge >> 2;
    const int es = (ge & 3) ^ ((er >> 1) & 3);
    const int rw = t >> 3, hh = t & 7;
    const int wChunkByte = rw * 64 + (((hh >> 1) ^ ((rw >> 1) & 3)) * 16) + (hh & 1) * 8;

#define STAGE_PV(buf, kk) do {                                                 \
    _Pragma("unroll")                                                          \
    for (int i_ = 0; i_ < 4; ++i_) {                                           \
        int g_ = t + i_ * 512;                                                 \
        int vr_ = g_ >> 2;                                                     \
        int vs_ = (g_ & 3) ^ ((vr_ >> 1) & 3);                                 \
        gload16(&Vb[(size_t)vr_ * S_ + (kk) + vs_ * 8], (char*)Vh[buf] + (size_t)g_ * 16); \
    }                                                                          \
    if (doE)                                                                   \
        gload16(WbB + (size_t)er * 8192 + 4096 + 2 * (kk) + es * 16,           \
                (char*)Wh[buf] + ge * 16);                                     \
} while (0)

    // ---- Phase A: per-q softmax stats combine
    if (t < 64) {
        float mkb[16], skb[16];
        float m = -1e30f;
        #pragma unroll
        for (int kb = 0; kb < 16; ++kb) {
            float2 st = stats[(size_t)(b * 16 + kb) * S_ + qBase + t];
            mkb[kb] = st.x; skb[kb] = st.y;
            m = fmaxf(m, st.x);
        }
        float s = 0.f;
        #pragma unroll
        for (int kb = 0; kb < 16; ++kb) {
            mkb[kb] = __expf(mkb[kb] - m);
            s += skb[kb] * mkb[kb];
        }
        const float inv = 1.0f / s;
        #pragma unroll
        for (int kb = 0; kb < 16; ++kb) smScale[kb][t] = mkb[kb] * inv;
    }

    floatx4 acc[4][4] = {};

    STAGE_PV(0, 0);
    __syncthreads();   // full drain once; publishes smScale + buf0

    for (int step = 0; step < 64; ++step) {
        const int cur = step & 1;
        const int kk = step * 32;
        const int kblk = kk >> 7;
        // stage next tile (5 vmem ops for waves 0-3, 4 for waves 4-7)
        if (step < 63) STAGE_PV(cur ^ 1, kk + 32);
        // fused fp32 weights write — the NEWEST vmem op this step
        {
            half4 eh = *(half4*)((char*)Wh[cur] + wChunkByte);
            const float scw = smScale[kblk][rw];
            float4 w;
            w.x = (float)eh[0] * scw;
            w.y = (float)eh[1] * scw;
            w.z = (float)eh[2] * scw;
            w.w = (float)eh[3] * scw;
            *(float4*)(WbB + (size_t)rw * 8192 + 4 * (kk + hh * 4)) = w;
        }
        half8 af[4], bf[4];
        #pragma unroll
        for (int mi = 0; mi < 4; ++mi) {
            int row = wv * 64 + mi * 16 + fr;
            int c = fk4 ^ ((row >> 1) & 3);
            af[mi] = *(half8*)&Vh[cur][row * 32 + c * 8];
        }
        #pragma unroll
        for (int ni = 0; ni < 4; ++ni) {
            int row = ni * 16 + fr;
            int c = fk4 ^ ((row >> 1) & 3);
            bf[ni] = *(half8*)&Wh[cur][row * 32 + c * 8];
            const _Float16 sch = (_Float16)smScale[kblk][row];
            #pragma unroll
            for (int j = 0; j < 8; ++j) bf[ni][j] *= sch;
        }
        __builtin_amdgcn_s_setprio(1);
        #pragma unroll
        for (int mi = 0; mi < 4; ++mi)
            #pragma unroll
            for (int ni = 0; ni < 4; ++ni)
                acc[mi][ni] = mfma16(af[mi], bf[ni], acc[mi][ni]);
        __builtin_amdgcn_s_setprio(0);
        // drain the stage ops, keep the w-store in flight
        WAITB(1);
    }
#undef STAGE_PV

    #pragma unroll
    for (int mi = 0; mi < 4; ++mi) {
        #pragma unroll
        for (int ni = 0; ni < 4; ++ni) {
            const int d0 = wv * 64 + mi * 16 + (l >> 4) * 4;
            const int q  = qBase + ni * 16 + fr;
            float4 v;
            v.x = acc[mi][ni][0];
            v.y = acc[mi][ni][1];
            v.z = acc[mi][ni][2];
            v.w = acc[mi][ni][3];
            *(float4*)&Out[((size_t)b * S_ + q) * D_ + d0] = v;
        }
    }
}

// ---------------------------------------------------------------------------
extern "C" void kernel_launch(void* const* d_in, const int* in_sizes, int n_in,
                              void* d_out, int out_size, void* d_ws, size_t ws_size,
                              hipStream_t stream)
{
    const float* x  = (const float*)d_in[0];
    const float* Wq = (const float*)d_in[1];
    const float* bq = (const float*)d_in[2];
    const float* Wk = (const float*)d_in[3];
    const float* bk = (const float*)d_in[4];
    const float* Wv = (const float*)d_in[5];
    const float* bv = (const float*)d_in[6];

    float* out = (float*)d_out;                       // [16,2048,512]
    float* wts = out + (size_t)B_ * S_ * D_;          // [16,2048,2048]

    _Float16* Qh = (_Float16*)d_ws;                   // 32 MB
    _Float16* Kh = Qh + (size_t)MTOT * D_;            // 32 MB
    _Float16* Vt = Kh + (size_t)MTOT * D_;            // 32 MB
    float2* stats = (float2*)(Vt + (size_t)MTOT * D_); // 4 MB

    // fp16 scratch inside the weights output region (dead until scores runs)
    _Float16* xh  = (_Float16*)wts;                   // 33.5 MB
    _Float16* wh3 = xh + (size_t)MTOT * D_;           // 1.5 MB

    cvt_x_kernel<<<MTOT * D_ / (256 * 8), 256, 0, stream>>>(x, xh);
    cvt_w_kernel<<<3 * D_ * D_ / (256 * 8), 256, 0, stream>>>(Wq, Wk, Wv, wh3);
    proj2_kernel<<<dim3(D_ / 128, MTOT / 128, 3), 256, 0, stream>>>(
        xh, wh3, bq, bk, bv, Qh, Kh, Vt);
    scores_kernel<<<4096, 256, 0, stream>>>(Qh, Kh, wts, stats);
    pv8<<<512, 512, 0, stream>>>(wts, Vt, stats, out);
}